// Round 1
// baseline (205.249 us; speedup 1.0000x reference)
//
#include <hip/hip_runtime.h>
#include <math.h>

#define N_G   2048
#define IMG_W 128
#define IMG_H 128
#define SEGS  4
#define SEG_LEN (N_G / SEGS)
#define NPIX (IMG_W * IMG_H)

// ---------------------------------------------------------------------------
// Kernel 1: per-splat preprocessing. One thread per gaussian.
// Writes: areas (to d_out, original order), depths, packed[12] per splat:
//   {ux, uy, cinv0, cinv1, cinv2, alpha_eff, col0, col1, col2, 0, 0, 0}
// alpha_eff = 0 for invalid splats (then g < 1/255 masks them, same as v_s).
// ---------------------------------------------------------------------------
__global__ __launch_bounds__(256) void preprocess_k(
    const float* __restrict__ pws, const float* __restrict__ shs,
    const float* __restrict__ alphas_raw, const float* __restrict__ scales_raw,
    const float* __restrict__ rots_raw, const float* __restrict__ Rcw,
    const float* __restrict__ tcw,
    const int* __restrict__ fxp, const int* __restrict__ fyp,
    const int* __restrict__ cxp, const int* __restrict__ cyp,
    float* __restrict__ areas, float* __restrict__ depths,
    float* __restrict__ packed)
{
    int i = blockIdx.x * blockDim.x + threadIdx.x;
    if (i >= N_G) return;

    const float fx = (float)fxp[0], fy = (float)fyp[0];
    const float cx = (float)cxp[0], cy = (float)cyp[0];
    const float R00 = Rcw[0], R01 = Rcw[1], R02 = Rcw[2];
    const float R10 = Rcw[3], R11 = Rcw[4], R12 = Rcw[5];
    const float R20 = Rcw[6], R21 = Rcw[7], R22 = Rcw[8];
    const float t0 = tcw[0], t1 = tcw[1], t2 = tcw[2];

    const float pwx = pws[i * 3 + 0], pwy = pws[i * 3 + 1], pwz = pws[i * 3 + 2];

    // pcs = Rcw @ pw + tcw
    const float pcx = R00 * pwx + R01 * pwy + R02 * pwz + t0;
    const float pcy = R10 * pwx + R11 * pwy + R12 * pwz + t1;
    const float pcz = R20 * pwx + R21 * pwy + R22 * pwz + t2;

    const float depth = pcz;
    bool valid = depth > 0.2f;
    const float z = valid ? depth : 1.0f;

    const float ux = fx * pcx / z + cx;
    const float uy = fy * pcy / z + cy;

    // quaternion -> rotation
    float qw = rots_raw[i * 4 + 0], qx = rots_raw[i * 4 + 1];
    float qy = rots_raw[i * 4 + 2], qz = rots_raw[i * 4 + 3];
    const float qn = sqrtf(qw * qw + qx * qx + qy * qy + qz * qz);
    qw /= qn; qx /= qn; qy /= qn; qz /= qn;
    float Rr[3][3];
    Rr[0][0] = 1.f - 2.f * (qy * qy + qz * qz);
    Rr[0][1] = 2.f * (qx * qy - qw * qz);
    Rr[0][2] = 2.f * (qx * qz + qw * qy);
    Rr[1][0] = 2.f * (qx * qy + qw * qz);
    Rr[1][1] = 1.f - 2.f * (qx * qx + qz * qz);
    Rr[1][2] = 2.f * (qy * qz - qw * qx);
    Rr[2][0] = 2.f * (qx * qz - qw * qy);
    Rr[2][1] = 2.f * (qy * qz + qw * qx);
    Rr[2][2] = 1.f - 2.f * (qx * qx + qy * qy);

    const float s0 = expf(scales_raw[i * 3 + 0]);
    const float s1 = expf(scales_raw[i * 3 + 1]);
    const float s2 = expf(scales_raw[i * 3 + 2]);
    const float sc[3] = { s0, s1, s2 };

    float M[3][3];
    for (int r = 0; r < 3; ++r)
        for (int c = 0; c < 3; ++c) M[r][c] = Rr[r][c] * sc[c];

    float cov[3][3];
    for (int r = 0; r < 3; ++r)
        for (int c = 0; c < 3; ++c)
            cov[r][c] = M[r][0] * M[c][0] + M[r][1] * M[c][1] + M[r][2] * M[c][2];

    // J (2x3), T = J @ Rcw
    const float limx = 1.3f * 0.5f * (float)IMG_W / fx;
    const float limy = 1.3f * 0.5f * (float)IMG_H / fy;
    const float xz_ = pcx / z, yz_ = pcy / z;
    const float tx = fminf(fmaxf(xz_, -limx), limx) * z;
    const float ty = fminf(fmaxf(yz_, -limy), limy) * z;
    const float J00 = fx / z, J02 = -fx * tx / (z * z);
    const float J11 = fy / z, J12 = -fy * ty / (z * z);
    const float T00 = J00 * R00 + J02 * R20;
    const float T01 = J00 * R01 + J02 * R21;
    const float T02 = J00 * R02 + J02 * R22;
    const float T10 = J11 * R10 + J12 * R20;
    const float T11 = J11 * R11 + J12 * R21;
    const float T12 = J11 * R12 + J12 * R22;

    // cov2d = T cov T^T + 0.3 I
    float tmp0[3], tmp1[3];
    for (int k = 0; k < 3; ++k) {
        tmp0[k] = T00 * cov[0][k] + T01 * cov[1][k] + T02 * cov[2][k];
        tmp1[k] = T10 * cov[0][k] + T11 * cov[1][k] + T12 * cov[2][k];
    }
    const float a = tmp0[0] * T00 + tmp0[1] * T01 + tmp0[2] * T02 + 0.3f;
    const float b = tmp0[0] * T10 + tmp0[1] * T11 + tmp0[2] * T12;
    const float c = tmp1[0] * T10 + tmp1[1] * T11 + tmp1[2] * T12 + 0.3f;

    // view dirs: twc = -Rcw^T tcw, d = pw - twc
    const float twx = -(R00 * t0 + R10 * t1 + R20 * t2);
    const float twy = -(R01 * t0 + R11 * t1 + R21 * t2);
    const float twz = -(R02 * t0 + R12 * t1 + R22 * t2);
    const float ddx = pwx - twx, ddy = pwy - twy, ddz = pwz - twz;
    const float dn = sqrtf(ddx * ddx + ddy * ddy + ddz * ddz);
    const float dirx = ddx / dn, diry = ddy / dn, dirz = ddz / dn;

    // SH (deg 3) basis
    const float xx = dirx * dirx, yy = diry * diry, zz = dirz * dirz;
    const float xy = dirx * diry, yz = diry * dirz, xz = dirx * dirz;
    float bf[16];
    bf[0]  = 0.28209479177387814f;
    bf[1]  = -0.4886025119029199f * diry;
    bf[2]  = 0.4886025119029199f * dirz;
    bf[3]  = -0.4886025119029199f * dirx;
    bf[4]  = 1.0925484305920792f * xy;
    bf[5]  = -1.0925484305920792f * yz;
    bf[6]  = 0.31539156525252005f * (2.f * zz - xx - yy);
    bf[7]  = -1.0925484305920792f * xz;
    bf[8]  = 0.5462742152960396f * (xx - yy);
    bf[9]  = -0.5900435899266435f * diry * (3.f * xx - yy);
    bf[10] = 2.890611442640554f * xy * dirz;
    bf[11] = -0.4570457994644658f * diry * (4.f * zz - xx - yy);
    bf[12] = 0.3731763325901154f * dirz * (2.f * zz - 3.f * xx - 3.f * yy);
    bf[13] = -0.4570457994644658f * dirx * (4.f * zz - xx - yy);
    bf[14] = 1.445305721320277f * dirz * (xx - yy);
    bf[15] = -0.5900435899266435f * dirx * (xx - 3.f * yy);

    float col[3];
    for (int ch = 0; ch < 3; ++ch) {
        float acc = 0.f;
        for (int k = 0; k < 16; ++k) acc += bf[k] * shs[i * 48 + k * 3 + ch];
        col[ch] = fmaxf(acc + 0.5f, 0.f);
    }

    const float det = a * c - b * b;
    valid = valid && (det > 0.f);
    const float det_s = valid ? det : 1.0f;
    const float ci0 = c / det_s, ci1 = -b / det_s, ci2 = a / det_s;

    const float mid  = 0.5f * (a + c);
    const float disc = sqrtf(fmaxf(mid * mid - det, 0.1f));
    const float a0 = 3.f * sqrtf(fmaxf(mid + disc, 0.f));
    const float a1 = 3.f * sqrtf(fmaxf(mid - disc, 0.f));
    areas[i * 2 + 0] = valid ? a0 : 0.f;
    areas[i * 2 + 1] = valid ? a1 : 0.f;

    const float alpha = 1.f / (1.f + expf(-alphas_raw[i]));

    depths[i] = depth;
    float* pk = packed + i * 12;
    pk[0] = ux;  pk[1] = uy;
    pk[2] = ci0; pk[3] = ci1; pk[4] = ci2;
    pk[5] = valid ? alpha : 0.f;
    pk[6] = col[0]; pk[7] = col[1]; pk[8] = col[2];
    pk[9] = 0.f; pk[10] = 0.f; pk[11] = 0.f;
}

// ---------------------------------------------------------------------------
// Kernel 2: stable O(N^2) rank sort by depth + scatter packed records.
// Matches jnp.argsort (stable ascending) exactly.
// ---------------------------------------------------------------------------
__global__ __launch_bounds__(256) void sort_scatter_k(
    const float* __restrict__ depths, const float* __restrict__ packed,
    float* __restrict__ sorted)
{
    __shared__ float sd[N_G];
    const int tid = threadIdx.x;
    for (int k = tid; k < N_G; k += 256) sd[k] = depths[k];
    __syncthreads();

    const int i = blockIdx.x * 256 + tid;
    const float d = sd[i];
    int r = 0;
    for (int j = 0; j < N_G; ++j) {
        const float dj = sd[j];
        r += (dj < d) || (dj == d && j < i);
    }
    const float* src = packed + i * 12;
    float* dst = sorted + r * 12;
    #pragma unroll
    for (int k = 0; k < 12; ++k) dst[k] = src[k];
}

// ---------------------------------------------------------------------------
// Kernel 3: rasterize. 256 blocks x 256 threads.
// Block handles 64 pixels; wave s (of 4) composites gaussian segment
// [s*512, (s+1)*512) for those pixels. Segments combined via
// (C,T) ⊕ (C',T') = (C + T*C', T*T') — associative, so this equals the
// full front-to-back cumprod composite.
// ---------------------------------------------------------------------------
__global__ __launch_bounds__(256) void raster_k(
    const float* __restrict__ sorted, float* __restrict__ image)
{
    const int lane = threadIdx.x & 63;
    const int seg  = threadIdx.x >> 6;
    const int p    = blockIdx.x * 64 + lane;
    const float px = (float)(p & (IMG_W - 1)) + 0.5f;
    const float py = (float)(p >> 7) + 0.5f;

    float T = 1.f, C0 = 0.f, C1 = 0.f, C2 = 0.f;
    const float* gp = sorted + seg * SEG_LEN * 12;
    for (int j = 0; j < SEG_LEN; ++j, gp += 12) {
        const float ux = gp[0], uy = gp[1];
        const float c0 = gp[2], c1 = gp[3], c2 = gp[4];
        const float al = gp[5];
        const float cr = gp[6], cg = gp[7], cb = gp[8];

        const float dx = px - ux, dy = py - uy;
        const float power = -0.5f * (c0 * dx * dx + c2 * dy * dy) - c1 * dx * dy;
        const float e = __expf(fminf(power, 0.f));
        float g = fminf(al * e, 0.99f);
        const bool ok = (power <= 0.f) && (g >= (1.f / 255.f));
        g = ok ? g : 0.f;
        const float w = T * g;
        C0 += w * cr; C1 += w * cg; C2 += w * cb;
        T *= (1.f - g);
    }

    __shared__ float red[SEGS][64][4];
    red[seg][lane][0] = C0;
    red[seg][lane][1] = C1;
    red[seg][lane][2] = C2;
    red[seg][lane][3] = T;
    __syncthreads();

    if (seg == 0) {
        float Tacc = 1.f, A0 = 0.f, A1 = 0.f, A2 = 0.f;
        #pragma unroll
        for (int s = 0; s < SEGS; ++s) {
            A0 += Tacc * red[s][lane][0];
            A1 += Tacc * red[s][lane][1];
            A2 += Tacc * red[s][lane][2];
            Tacc *= red[s][lane][3];
        }
        image[p]            = A0;
        image[NPIX + p]     = A1;
        image[2 * NPIX + p] = A2;
    }
}

// ---------------------------------------------------------------------------
extern "C" void kernel_launch(void* const* d_in, const int* in_sizes, int n_in,
                              void* d_out, int out_size, void* d_ws, size_t ws_size,
                              hipStream_t stream) {
    const float* pws        = (const float*)d_in[0];
    const float* shs        = (const float*)d_in[1];
    const float* alphas_raw = (const float*)d_in[2];
    const float* scales_raw = (const float*)d_in[3];
    const float* rots_raw   = (const float*)d_in[4];
    // d_in[5] = us (unused by reference)
    const float* Rcw        = (const float*)d_in[6];
    const float* tcw        = (const float*)d_in[7];
    const int*   fxp        = (const int*)d_in[8];
    const int*   fyp        = (const int*)d_in[9];
    const int*   cxp        = (const int*)d_in[10];
    const int*   cyp        = (const int*)d_in[11];
    // d_in[12] = width (128), d_in[13] = height (128) — compile-time here.

    float* out   = (float*)d_out;
    float* areas = out + 3 * NPIX;          // image first, then areas

    float* depths = (float*)d_ws;           // N floats
    float* packed = depths + N_G;           // N*12 floats
    float* sorted = packed + N_G * 12;      // N*12 floats

    preprocess_k<<<N_G / 256, 256, 0, stream>>>(
        pws, shs, alphas_raw, scales_raw, rots_raw, Rcw, tcw,
        fxp, fyp, cxp, cyp, areas, depths, packed);

    sort_scatter_k<<<N_G / 256, 256, 0, stream>>>(depths, packed, sorted);

    raster_k<<<NPIX / 64, 256, 0, stream>>>(sorted, out);
}

// Round 2
// 163.766 us; speedup vs baseline: 1.2533x; 1.2533x over previous
//
#include <hip/hip_runtime.h>
#include <hip/hip_fp16.h>
#include <math.h>

#define N_G   2048
#define IMG_W 128
#define IMG_H 128
#define NPIX (IMG_W * IMG_H)

// raster decomposition:
#define SUPER   4                 // super-segments (cross-block, combined by combine_k)
#define WPB     4                 // waves per block = sub-segments per super-segment
#define SUPER_LEN (N_G / SUPER)   // 512 splats staged per block
#define SUB_LEN   (SUPER_LEN / WPB) // 128 splats per wave

// packed record: 8 floats = 32 B
//  [0]=ux [1]=uy [2]=n0(-0.5*ci0) [3]=n1(-ci1) [4]=n2(-0.5*ci2)
//  [5]=alpha_eff [6]=half2(col0,col1) [7]=col2
#define REC_F4 2

union f2h2 { float f; __half2 h; };

// ---------------------------------------------------------------------------
// Kernel 1: per-splat preprocessing.
// ---------------------------------------------------------------------------
__global__ __launch_bounds__(256) void preprocess_k(
    const float* __restrict__ pws, const float* __restrict__ shs,
    const float* __restrict__ alphas_raw, const float* __restrict__ scales_raw,
    const float* __restrict__ rots_raw, const float* __restrict__ Rcw,
    const float* __restrict__ tcw,
    const int* __restrict__ fxp, const int* __restrict__ fyp,
    const int* __restrict__ cxp, const int* __restrict__ cyp,
    float* __restrict__ areas, float* __restrict__ depths,
    float* __restrict__ packed)
{
    int i = blockIdx.x * blockDim.x + threadIdx.x;
    if (i >= N_G) return;

    const float fx = (float)fxp[0], fy = (float)fyp[0];
    const float cx = (float)cxp[0], cy = (float)cyp[0];
    const float R00 = Rcw[0], R01 = Rcw[1], R02 = Rcw[2];
    const float R10 = Rcw[3], R11 = Rcw[4], R12 = Rcw[5];
    const float R20 = Rcw[6], R21 = Rcw[7], R22 = Rcw[8];
    const float t0 = tcw[0], t1 = tcw[1], t2 = tcw[2];

    const float pwx = pws[i * 3 + 0], pwy = pws[i * 3 + 1], pwz = pws[i * 3 + 2];

    const float pcx = R00 * pwx + R01 * pwy + R02 * pwz + t0;
    const float pcy = R10 * pwx + R11 * pwy + R12 * pwz + t1;
    const float pcz = R20 * pwx + R21 * pwy + R22 * pwz + t2;

    const float depth = pcz;
    bool valid = depth > 0.2f;
    const float z = valid ? depth : 1.0f;

    const float ux = fx * pcx / z + cx;
    const float uy = fy * pcy / z + cy;

    float qw = rots_raw[i * 4 + 0], qx = rots_raw[i * 4 + 1];
    float qy = rots_raw[i * 4 + 2], qz = rots_raw[i * 4 + 3];
    const float qn = sqrtf(qw * qw + qx * qx + qy * qy + qz * qz);
    qw /= qn; qx /= qn; qy /= qn; qz /= qn;
    float Rr[3][3];
    Rr[0][0] = 1.f - 2.f * (qy * qy + qz * qz);
    Rr[0][1] = 2.f * (qx * qy - qw * qz);
    Rr[0][2] = 2.f * (qx * qz + qw * qy);
    Rr[1][0] = 2.f * (qx * qy + qw * qz);
    Rr[1][1] = 1.f - 2.f * (qx * qx + qz * qz);
    Rr[1][2] = 2.f * (qy * qz - qw * qx);
    Rr[2][0] = 2.f * (qx * qz - qw * qy);
    Rr[2][1] = 2.f * (qy * qz + qw * qx);
    Rr[2][2] = 1.f - 2.f * (qx * qx + qy * qy);

    const float s0 = expf(scales_raw[i * 3 + 0]);
    const float s1 = expf(scales_raw[i * 3 + 1]);
    const float s2 = expf(scales_raw[i * 3 + 2]);
    const float sc[3] = { s0, s1, s2 };

    float M[3][3];
    for (int r = 0; r < 3; ++r)
        for (int c = 0; c < 3; ++c) M[r][c] = Rr[r][c] * sc[c];

    float cov[3][3];
    for (int r = 0; r < 3; ++r)
        for (int c = 0; c < 3; ++c)
            cov[r][c] = M[r][0] * M[c][0] + M[r][1] * M[c][1] + M[r][2] * M[c][2];

    const float limx = 1.3f * 0.5f * (float)IMG_W / fx;
    const float limy = 1.3f * 0.5f * (float)IMG_H / fy;
    const float xz_ = pcx / z, yz_ = pcy / z;
    const float tx = fminf(fmaxf(xz_, -limx), limx) * z;
    const float ty = fminf(fmaxf(yz_, -limy), limy) * z;
    const float J00 = fx / z, J02 = -fx * tx / (z * z);
    const float J11 = fy / z, J12 = -fy * ty / (z * z);
    const float T00 = J00 * R00 + J02 * R20;
    const float T01 = J00 * R01 + J02 * R21;
    const float T02 = J00 * R02 + J02 * R22;
    const float T10 = J11 * R10 + J12 * R20;
    const float T11 = J11 * R11 + J12 * R21;
    const float T12 = J11 * R12 + J12 * R22;

    float tmp0[3], tmp1[3];
    for (int k = 0; k < 3; ++k) {
        tmp0[k] = T00 * cov[0][k] + T01 * cov[1][k] + T02 * cov[2][k];
        tmp1[k] = T10 * cov[0][k] + T11 * cov[1][k] + T12 * cov[2][k];
    }
    const float a = tmp0[0] * T00 + tmp0[1] * T01 + tmp0[2] * T02 + 0.3f;
    const float b = tmp0[0] * T10 + tmp0[1] * T11 + tmp0[2] * T12;
    const float c = tmp1[0] * T10 + tmp1[1] * T11 + tmp1[2] * T12 + 0.3f;

    const float twx = -(R00 * t0 + R10 * t1 + R20 * t2);
    const float twy = -(R01 * t0 + R11 * t1 + R21 * t2);
    const float twz = -(R02 * t0 + R12 * t1 + R22 * t2);
    const float ddx = pwx - twx, ddy = pwy - twy, ddz = pwz - twz;
    const float dn = sqrtf(ddx * ddx + ddy * ddy + ddz * ddz);
    const float dirx = ddx / dn, diry = ddy / dn, dirz = ddz / dn;

    const float xx = dirx * dirx, yy = diry * diry, zz = dirz * dirz;
    const float xy = dirx * diry, yz = diry * dirz, xz = dirx * dirz;
    float bf[16];
    bf[0]  = 0.28209479177387814f;
    bf[1]  = -0.4886025119029199f * diry;
    bf[2]  = 0.4886025119029199f * dirz;
    bf[3]  = -0.4886025119029199f * dirx;
    bf[4]  = 1.0925484305920792f * xy;
    bf[5]  = -1.0925484305920792f * yz;
    bf[6]  = 0.31539156525252005f * (2.f * zz - xx - yy);
    bf[7]  = -1.0925484305920792f * xz;
    bf[8]  = 0.5462742152960396f * (xx - yy);
    bf[9]  = -0.5900435899266435f * diry * (3.f * xx - yy);
    bf[10] = 2.890611442640554f * xy * dirz;
    bf[11] = -0.4570457994644658f * diry * (4.f * zz - xx - yy);
    bf[12] = 0.3731763325901154f * dirz * (2.f * zz - 3.f * xx - 3.f * yy);
    bf[13] = -0.4570457994644658f * dirx * (4.f * zz - xx - yy);
    bf[14] = 1.445305721320277f * dirz * (xx - yy);
    bf[15] = -0.5900435899266435f * dirx * (xx - 3.f * yy);

    float col[3];
    for (int ch = 0; ch < 3; ++ch) {
        float acc = 0.f;
        for (int k = 0; k < 16; ++k) acc += bf[k] * shs[i * 48 + k * 3 + ch];
        col[ch] = fmaxf(acc + 0.5f, 0.f);
    }

    const float det = a * c - b * b;
    valid = valid && (det > 0.f);
    const float det_s = valid ? det : 1.0f;
    const float ci0 = c / det_s, ci1 = -b / det_s, ci2 = a / det_s;

    const float mid  = 0.5f * (a + c);
    const float disc = sqrtf(fmaxf(mid * mid - det, 0.1f));
    const float a0 = 3.f * sqrtf(fmaxf(mid + disc, 0.f));
    const float a1 = 3.f * sqrtf(fmaxf(mid - disc, 0.f));
    areas[i * 2 + 0] = valid ? a0 : 0.f;
    areas[i * 2 + 1] = valid ? a1 : 0.f;

    const float alpha = 1.f / (1.f + expf(-alphas_raw[i]));

    depths[i] = depth;

    f2h2 pc; pc.h = __floats2half2_rn(col[0], col[1]);
    float* pk = packed + i * 8;
    pk[0] = ux;  pk[1] = uy;
    pk[2] = -0.5f * ci0; pk[3] = -ci1; pk[4] = -0.5f * ci2;
    pk[5] = valid ? alpha : 0.f;
    pk[6] = pc.f;
    pk[7] = col[2];
}

// ---------------------------------------------------------------------------
// Kernel 2: stable O(N^2) rank sort by depth + scatter packed records.
// ---------------------------------------------------------------------------
__global__ __launch_bounds__(256) void sort_scatter_k(
    const float* __restrict__ depths, const float4* __restrict__ packed,
    float4* __restrict__ sorted)
{
    __shared__ float sd[N_G];
    const int tid = threadIdx.x;
    for (int k = tid; k < N_G; k += 256) sd[k] = depths[k];
    __syncthreads();

    const int i = blockIdx.x * 256 + tid;
    const float d = sd[i];
    int r = 0;
    for (int j = 0; j < N_G; ++j) {
        const float dj = sd[j];
        r += (dj < d) || (dj == d && j < i);
    }
    sorted[r * 2 + 0] = packed[i * 2 + 0];
    sorted[r * 2 + 1] = packed[i * 2 + 1];
}

// ---------------------------------------------------------------------------
// Kernel 3: rasterize. Grid = 256 pixel-groups x SUPER blocks, 256 threads.
// Block (pg, sb): stages super-segment sb (512 records, 16 KB) in LDS;
// wave w composites sub-segment [sb*512 + w*128, +128) for 64 pixels;
// block combines its 4 waves in order, writes one partial per pixel.
// ---------------------------------------------------------------------------
__global__ __launch_bounds__(256) void raster_k(
    const float4* __restrict__ sorted, float4* __restrict__ partial)
{
    __shared__ float4 sg[SUPER_LEN * REC_F4];      // 16 KB
    __shared__ float red[WPB][64][4];              // 4 KB

    const int pg   = blockIdx.x & 255;
    const int sb   = blockIdx.x >> 8;
    const int tid  = threadIdx.x;
    const int lane = tid & 63;
    const int w    = tid >> 6;

    // stage super-segment: 1024 float4s, coalesced
    const float4* src = sorted + sb * (SUPER_LEN * REC_F4);
    #pragma unroll
    for (int k = 0; k < 4; ++k)
        sg[tid + k * 256] = src[tid + k * 256];
    __syncthreads();

    const int p = pg * 64 + lane;
    const float px = (float)(p & (IMG_W - 1)) + 0.5f;
    const float py = (float)(p >> 7) + 0.5f;

    float T = 1.f, C0 = 0.f, C1 = 0.f, C2 = 0.f;
    const int base = w * SUB_LEN * REC_F4;
    #pragma unroll 4
    for (int j = 0; j < SUB_LEN; ++j) {
        const float4 r0 = sg[base + j * 2 + 0];
        const float4 r1 = sg[base + j * 2 + 1];
        const float dx = px - r0.x, dy = py - r0.y;
        const float power = r0.z * (dx * dx) + r0.w * (dx * dy) + r1.x * (dy * dy);
        const float e = __expf(fminf(power, 0.f));
        float g = fminf(r1.y * e, 0.99f);
        const bool ok = (power <= 0.f) && (g >= (1.f / 255.f));
        g = ok ? g : 0.f;
        const float wgt = T * g;
        f2h2 cu; cu.f = r1.z;
        const float c0f = __low2float(cu.h), c1f = __high2float(cu.h);
        C0 += wgt * c0f; C1 += wgt * c1f; C2 += wgt * r1.w;
        T *= (1.f - g);
    }

    red[w][lane][0] = C0;
    red[w][lane][1] = C1;
    red[w][lane][2] = C2;
    red[w][lane][3] = T;
    __syncthreads();

    if (w == 0) {
        float Tacc = 1.f, A0 = 0.f, A1 = 0.f, A2 = 0.f;
        #pragma unroll
        for (int s = 0; s < WPB; ++s) {
            A0 += Tacc * red[s][lane][0];
            A1 += Tacc * red[s][lane][1];
            A2 += Tacc * red[s][lane][2];
            Tacc *= red[s][lane][3];
        }
        partial[sb * NPIX + p] = make_float4(A0, A1, A2, Tacc);
    }
}

// ---------------------------------------------------------------------------
// Kernel 4: ordered combine of SUPER partials per pixel -> planar image.
// ---------------------------------------------------------------------------
__global__ __launch_bounds__(256) void combine_k(
    const float4* __restrict__ partial, float* __restrict__ image)
{
    const int p = blockIdx.x * 256 + threadIdx.x;
    float Tacc = 1.f, A0 = 0.f, A1 = 0.f, A2 = 0.f;
    #pragma unroll
    for (int s = 0; s < SUPER; ++s) {
        const float4 v = partial[s * NPIX + p];
        A0 += Tacc * v.x;
        A1 += Tacc * v.y;
        A2 += Tacc * v.z;
        Tacc *= v.w;
    }
    image[p]            = A0;
    image[NPIX + p]     = A1;
    image[2 * NPIX + p] = A2;
}

// ---------------------------------------------------------------------------
extern "C" void kernel_launch(void* const* d_in, const int* in_sizes, int n_in,
                              void* d_out, int out_size, void* d_ws, size_t ws_size,
                              hipStream_t stream) {
    const float* pws        = (const float*)d_in[0];
    const float* shs        = (const float*)d_in[1];
    const float* alphas_raw = (const float*)d_in[2];
    const float* scales_raw = (const float*)d_in[3];
    const float* rots_raw   = (const float*)d_in[4];
    const float* Rcw        = (const float*)d_in[6];
    const float* tcw        = (const float*)d_in[7];
    const int*   fxp        = (const int*)d_in[8];
    const int*   fyp        = (const int*)d_in[9];
    const int*   cxp        = (const int*)d_in[10];
    const int*   cyp        = (const int*)d_in[11];

    float* out   = (float*)d_out;
    float* areas = out + 3 * NPIX;

    float*  depths  = (float*)d_ws;                    // 2048 f
    float*  packed  = depths + N_G;                    // 2048*8 f
    float*  sorted  = packed + N_G * 8;                // 2048*8 f
    float4* partial = (float4*)(sorted + N_G * 8);     // SUPER*NPIX f4 (1 MB)

    preprocess_k<<<N_G / 256, 256, 0, stream>>>(
        pws, shs, alphas_raw, scales_raw, rots_raw, Rcw, tcw,
        fxp, fyp, cxp, cyp, areas, depths, packed);

    sort_scatter_k<<<N_G / 256, 256, 0, stream>>>(
        depths, (const float4*)packed, (float4*)sorted);

    raster_k<<<256 * SUPER, 256, 0, stream>>>((const float4*)sorted, partial);

    combine_k<<<NPIX / 256, 256, 0, stream>>>(partial, out);
}

// Round 3
// 111.059 us; speedup vs baseline: 1.8481x; 1.4746x over previous
//
#include <hip/hip_runtime.h>
#include <hip/hip_fp16.h>
#include <math.h>

#define N_G   2048
#define IMG_W 128
#define IMG_H 128
#define NPIX (IMG_W * IMG_H)

#define RWAVES 16                    // waves per raster block
#define RSUB   (N_G / RWAVES)        // 128 splats per wave

// packed record: 8 floats = 32 B
//  [0]=ux [1]=uy [2]=n0(-0.5*ci0) [3]=n1(-ci1) [4]=n2(-0.5*ci2)
//  [5]=alpha_eff [6]=half2(col0,col1) [7]=col2
union f2h2 { float f; __half2 h; };

// ---------------------------------------------------------------------------
// Kernel 1: per-splat preprocessing. 32 blocks x 64 threads.
// ---------------------------------------------------------------------------
__global__ __launch_bounds__(64) void preprocess_k(
    const float* __restrict__ pws, const float* __restrict__ shs,
    const float* __restrict__ alphas_raw, const float* __restrict__ scales_raw,
    const float* __restrict__ rots_raw, const float* __restrict__ Rcw,
    const float* __restrict__ tcw,
    const int* __restrict__ fxp, const int* __restrict__ fyp,
    const int* __restrict__ cxp, const int* __restrict__ cyp,
    float* __restrict__ areas, float* __restrict__ depths,
    float* __restrict__ packed)
{
    int i = blockIdx.x * 64 + threadIdx.x;
    if (i >= N_G) return;

    const float fx = (float)fxp[0], fy = (float)fyp[0];
    const float cx = (float)cxp[0], cy = (float)cyp[0];
    const float R00 = Rcw[0], R01 = Rcw[1], R02 = Rcw[2];
    const float R10 = Rcw[3], R11 = Rcw[4], R12 = Rcw[5];
    const float R20 = Rcw[6], R21 = Rcw[7], R22 = Rcw[8];
    const float t0 = tcw[0], t1 = tcw[1], t2 = tcw[2];

    const float pwx = pws[i * 3 + 0], pwy = pws[i * 3 + 1], pwz = pws[i * 3 + 2];

    const float pcx = R00 * pwx + R01 * pwy + R02 * pwz + t0;
    const float pcy = R10 * pwx + R11 * pwy + R12 * pwz + t1;
    const float pcz = R20 * pwx + R21 * pwy + R22 * pwz + t2;

    const float depth = pcz;
    bool valid = depth > 0.2f;
    const float z = valid ? depth : 1.0f;

    const float ux = fx * pcx / z + cx;
    const float uy = fy * pcy / z + cy;

    const float4 q4 = ((const float4*)rots_raw)[i];
    float qw = q4.x, qx = q4.y, qy = q4.z, qz = q4.w;
    const float qn = sqrtf(qw * qw + qx * qx + qy * qy + qz * qz);
    qw /= qn; qx /= qn; qy /= qn; qz /= qn;
    float Rr[3][3];
    Rr[0][0] = 1.f - 2.f * (qy * qy + qz * qz);
    Rr[0][1] = 2.f * (qx * qy - qw * qz);
    Rr[0][2] = 2.f * (qx * qz + qw * qy);
    Rr[1][0] = 2.f * (qx * qy + qw * qz);
    Rr[1][1] = 1.f - 2.f * (qx * qx + qz * qz);
    Rr[1][2] = 2.f * (qy * qz - qw * qx);
    Rr[2][0] = 2.f * (qx * qz - qw * qy);
    Rr[2][1] = 2.f * (qy * qz + qw * qx);
    Rr[2][2] = 1.f - 2.f * (qx * qx + qy * qy);

    const float s0 = expf(scales_raw[i * 3 + 0]);
    const float s1 = expf(scales_raw[i * 3 + 1]);
    const float s2 = expf(scales_raw[i * 3 + 2]);
    const float sc[3] = { s0, s1, s2 };

    float M[3][3];
    for (int r = 0; r < 3; ++r)
        for (int c = 0; c < 3; ++c) M[r][c] = Rr[r][c] * sc[c];

    float cov[3][3];
    for (int r = 0; r < 3; ++r)
        for (int c = 0; c < 3; ++c)
            cov[r][c] = M[r][0] * M[c][0] + M[r][1] * M[c][1] + M[r][2] * M[c][2];

    const float limx = 1.3f * 0.5f * (float)IMG_W / fx;
    const float limy = 1.3f * 0.5f * (float)IMG_H / fy;
    const float xz_ = pcx / z, yz_ = pcy / z;
    const float tx = fminf(fmaxf(xz_, -limx), limx) * z;
    const float ty = fminf(fmaxf(yz_, -limy), limy) * z;
    const float J00 = fx / z, J02 = -fx * tx / (z * z);
    const float J11 = fy / z, J12 = -fy * ty / (z * z);
    const float T00 = J00 * R00 + J02 * R20;
    const float T01 = J00 * R01 + J02 * R21;
    const float T02 = J00 * R02 + J02 * R22;
    const float T10 = J11 * R10 + J12 * R20;
    const float T11 = J11 * R11 + J12 * R21;
    const float T12 = J11 * R12 + J12 * R22;

    float tmp0[3], tmp1[3];
    for (int k = 0; k < 3; ++k) {
        tmp0[k] = T00 * cov[0][k] + T01 * cov[1][k] + T02 * cov[2][k];
        tmp1[k] = T10 * cov[0][k] + T11 * cov[1][k] + T12 * cov[2][k];
    }
    const float a = tmp0[0] * T00 + tmp0[1] * T01 + tmp0[2] * T02 + 0.3f;
    const float b = tmp0[0] * T10 + tmp0[1] * T11 + tmp0[2] * T12;
    const float c = tmp1[0] * T10 + tmp1[1] * T11 + tmp1[2] * T12 + 0.3f;

    const float twx = -(R00 * t0 + R10 * t1 + R20 * t2);
    const float twy = -(R01 * t0 + R11 * t1 + R21 * t2);
    const float twz = -(R02 * t0 + R12 * t1 + R22 * t2);
    const float ddx = pwx - twx, ddy = pwy - twy, ddz = pwz - twz;
    const float dn = sqrtf(ddx * ddx + ddy * ddy + ddz * ddz);
    const float dirx = ddx / dn, diry = ddy / dn, dirz = ddz / dn;

    const float xx = dirx * dirx, yy = diry * diry, zz = dirz * dirz;
    const float xy = dirx * diry, yz = diry * dirz, xz = dirx * dirz;
    float bf[16];
    bf[0]  = 0.28209479177387814f;
    bf[1]  = -0.4886025119029199f * diry;
    bf[2]  = 0.4886025119029199f * dirz;
    bf[3]  = -0.4886025119029199f * dirx;
    bf[4]  = 1.0925484305920792f * xy;
    bf[5]  = -1.0925484305920792f * yz;
    bf[6]  = 0.31539156525252005f * (2.f * zz - xx - yy);
    bf[7]  = -1.0925484305920792f * xz;
    bf[8]  = 0.5462742152960396f * (xx - yy);
    bf[9]  = -0.5900435899266435f * diry * (3.f * xx - yy);
    bf[10] = 2.890611442640554f * xy * dirz;
    bf[11] = -0.4570457994644658f * diry * (4.f * zz - xx - yy);
    bf[12] = 0.3731763325901154f * dirz * (2.f * zz - 3.f * xx - 3.f * yy);
    bf[13] = -0.4570457994644658f * dirx * (4.f * zz - xx - yy);
    bf[14] = 1.445305721320277f * dirz * (xx - yy);
    bf[15] = -0.5900435899266435f * dirx * (xx - 3.f * yy);

    // vectorized SH load: 48 contiguous floats = 12 float4
    float sh[48];
    const float4* sh4 = (const float4*)(shs + i * 48);
    #pragma unroll
    for (int k = 0; k < 12; ++k) ((float4*)sh)[k] = sh4[k];

    float col[3];
    for (int ch = 0; ch < 3; ++ch) {
        float acc = 0.f;
        #pragma unroll
        for (int k = 0; k < 16; ++k) acc += bf[k] * sh[k * 3 + ch];
        col[ch] = fmaxf(acc + 0.5f, 0.f);
    }

    const float det = a * c - b * b;
    valid = valid && (det > 0.f);
    const float det_s = valid ? det : 1.0f;
    const float ci0 = c / det_s, ci1 = -b / det_s, ci2 = a / det_s;

    const float mid  = 0.5f * (a + c);
    const float disc = sqrtf(fmaxf(mid * mid - det, 0.1f));
    const float a0 = 3.f * sqrtf(fmaxf(mid + disc, 0.f));
    const float a1 = 3.f * sqrtf(fmaxf(mid - disc, 0.f));
    areas[i * 2 + 0] = valid ? a0 : 0.f;
    areas[i * 2 + 1] = valid ? a1 : 0.f;

    const float alpha = 1.f / (1.f + expf(-alphas_raw[i]));

    depths[i] = depth;

    f2h2 pc; pc.h = __floats2half2_rn(col[0], col[1]);
    float* pk = packed + i * 8;
    pk[0] = ux;  pk[1] = uy;
    pk[2] = -0.5f * ci0; pk[3] = -ci1; pk[4] = -0.5f * ci2;
    pk[5] = valid ? alpha : 0.f;
    pk[6] = pc.f;
    pk[7] = col[2];
}

// ---------------------------------------------------------------------------
// Kernel 2: rank sort, wave-per-splat. 256 blocks x 512 threads.
// Wave w of block b ranks splat i = b*8+w: lanes split the j loop (32 iters),
// per-iter count via ballot+popc. Then lanes 0..1 scatter the 32 B record.
// Stable, matches jnp.argsort ascending exactly.
// ---------------------------------------------------------------------------
__global__ __launch_bounds__(512) void rank_scatter_k(
    const float* __restrict__ depths, const float4* __restrict__ packed,
    float4* __restrict__ sorted)
{
    __shared__ float sd[N_G];
    const int tid = threadIdx.x;
    ((float4*)sd)[tid] = ((const float4*)depths)[tid];   // 512 x float4 = 2048
    __syncthreads();

    const int w = tid >> 6, lane = tid & 63;
    const int i = blockIdx.x * 8 + w;
    const float d = sd[i];

    int r = 0;
    #pragma unroll 8
    for (int k = 0; k < 32; ++k) {
        const int j = k * 64 + lane;
        const float dj = sd[j];
        const bool c = (dj < d) || (dj == d && j < i);
        r += (int)__popcll(__ballot(c));
    }

    if (lane < 2)
        sorted[r * 2 + lane] = packed[i * 2 + lane];
}

// ---------------------------------------------------------------------------
// Kernel 3: rasterize, single pass. 256 blocks x 1024 threads (16 waves).
// Block stages ALL 2048 sorted records (64 KB LDS, coalesced). Wave w
// composites splats [w*128, w*128+128) for its 64 pixels; the 16 partials
// are combined in depth order via LDS (record buffer reused after sync).
// (C,T) ⊕ (C',T') = (C + T*C', T*T') is associative -> equals full cumprod.
// ---------------------------------------------------------------------------
__global__ __launch_bounds__(1024) void raster_k(
    const float4* __restrict__ sorted, float* __restrict__ image)
{
    __shared__ float4 sg[N_G * 2];               // 64 KB (reused for reduction)

    const int tid  = threadIdx.x;
    const int lane = tid & 63;
    const int w    = tid >> 6;

    #pragma unroll
    for (int k = 0; k < 4; ++k)
        sg[tid + k * 1024] = sorted[tid + k * 1024];
    __syncthreads();

    const int p = blockIdx.x * 64 + lane;
    const float px = (float)(p & (IMG_W - 1)) + 0.5f;
    const float py = (float)(p >> 7) + 0.5f;

    float T = 1.f, C0 = 0.f, C1 = 0.f, C2 = 0.f;
    const int base = w * RSUB * 2;
    #pragma unroll 4
    for (int j = 0; j < RSUB; ++j) {
        const float4 r0 = sg[base + j * 2 + 0];
        const float4 r1 = sg[base + j * 2 + 1];
        const float dx = px - r0.x, dy = py - r0.y;
        const float power = r0.z * (dx * dx) + r0.w * (dx * dy) + r1.x * (dy * dy);
        const float e = __expf(fminf(power, 0.f));
        float g = fminf(r1.y * e, 0.99f);
        const bool ok = (power <= 0.f) && (g >= (1.f / 255.f));
        g = ok ? g : 0.f;
        const float wgt = T * g;
        f2h2 cu; cu.f = r1.z;
        C0 += wgt * __low2float(cu.h);
        C1 += wgt * __high2float(cu.h);
        C2 += wgt * r1.w;
        T *= (1.f - g);
    }

    __syncthreads();                              // records no longer needed
    float4* red = sg;                             // [RWAVES][64] float4
    red[w * 64 + lane] = make_float4(C0, C1, C2, T);
    __syncthreads();

    if (w == 0) {
        float Tacc = 1.f, A0 = 0.f, A1 = 0.f, A2 = 0.f;
        #pragma unroll
        for (int s = 0; s < RWAVES; ++s) {
            const float4 v = red[s * 64 + lane];
            A0 += Tacc * v.x;
            A1 += Tacc * v.y;
            A2 += Tacc * v.z;
            Tacc *= v.w;
        }
        image[p]            = A0;
        image[NPIX + p]     = A1;
        image[2 * NPIX + p] = A2;
    }
}

// ---------------------------------------------------------------------------
extern "C" void kernel_launch(void* const* d_in, const int* in_sizes, int n_in,
                              void* d_out, int out_size, void* d_ws, size_t ws_size,
                              hipStream_t stream) {
    const float* pws        = (const float*)d_in[0];
    const float* shs        = (const float*)d_in[1];
    const float* alphas_raw = (const float*)d_in[2];
    const float* scales_raw = (const float*)d_in[3];
    const float* rots_raw   = (const float*)d_in[4];
    const float* Rcw        = (const float*)d_in[6];
    const float* tcw        = (const float*)d_in[7];
    const int*   fxp        = (const int*)d_in[8];
    const int*   fyp        = (const int*)d_in[9];
    const int*   cxp        = (const int*)d_in[10];
    const int*   cyp        = (const int*)d_in[11];

    float* out   = (float*)d_out;
    float* areas = out + 3 * NPIX;

    float* depths = (float*)d_ws;                  // 2048 f
    float* packed = depths + N_G;                  // 2048*8 f
    float* sorted = packed + N_G * 8;              // 2048*8 f

    preprocess_k<<<N_G / 64, 64, 0, stream>>>(
        pws, shs, alphas_raw, scales_raw, rots_raw, Rcw, tcw,
        fxp, fyp, cxp, cyp, areas, depths, packed);

    rank_scatter_k<<<N_G / 8, 512, 0, stream>>>(
        depths, (const float4*)packed, (float4*)sorted);

    raster_k<<<NPIX / 64, 1024, 0, stream>>>((const float4*)sorted, out);
}

// Round 4
// 90.914 us; speedup vs baseline: 2.2576x; 1.2216x over previous
//
#include <hip/hip_runtime.h>
#include <hip/hip_fp16.h>
#include <math.h>

#define N_G   2048
#define IMG_W 128
#define IMG_H 128
#define NPIX (IMG_W * IMG_H)

#define RWAVES 16                    // waves per raster block
#define RSUB   (N_G / RWAVES)        // 128 splats per wave

// packed record: 8 floats = 32 B
//  [0]=ux [1]=uy [2]=n0(-0.5*ci0) [3]=n1(-ci1) [4]=n2(-0.5*ci2)
//  [5]=alpha_eff [6]=half2(col0,col1) [7]=half2(col2, rad)
// rad = conservative influence radius (px); 0 => splat never passes the
// g>=1/255 mask anywhere (invalid, or alpha<1/255) -> cullable.
union f2h2 { float f; __half2 h; };

// ---------------------------------------------------------------------------
// Kernel 1: per-splat preprocessing. 32 blocks x 64 threads.
// ---------------------------------------------------------------------------
__global__ __launch_bounds__(64) void preprocess_k(
    const float* __restrict__ pws, const float* __restrict__ shs,
    const float* __restrict__ alphas_raw, const float* __restrict__ scales_raw,
    const float* __restrict__ rots_raw, const float* __restrict__ Rcw,
    const float* __restrict__ tcw,
    const int* __restrict__ fxp, const int* __restrict__ fyp,
    const int* __restrict__ cxp, const int* __restrict__ cyp,
    float* __restrict__ areas, float* __restrict__ depths,
    float* __restrict__ packed)
{
    int i = blockIdx.x * 64 + threadIdx.x;
    if (i >= N_G) return;

    const float fx = (float)fxp[0], fy = (float)fyp[0];
    const float cx = (float)cxp[0], cy = (float)cyp[0];
    const float R00 = Rcw[0], R01 = Rcw[1], R02 = Rcw[2];
    const float R10 = Rcw[3], R11 = Rcw[4], R12 = Rcw[5];
    const float R20 = Rcw[6], R21 = Rcw[7], R22 = Rcw[8];
    const float t0 = tcw[0], t1 = tcw[1], t2 = tcw[2];

    const float pwx = pws[i * 3 + 0], pwy = pws[i * 3 + 1], pwz = pws[i * 3 + 2];

    const float pcx = R00 * pwx + R01 * pwy + R02 * pwz + t0;
    const float pcy = R10 * pwx + R11 * pwy + R12 * pwz + t1;
    const float pcz = R20 * pwx + R21 * pwy + R22 * pwz + t2;

    const float depth = pcz;
    bool valid = depth > 0.2f;
    const float z = valid ? depth : 1.0f;

    const float ux = fx * pcx / z + cx;
    const float uy = fy * pcy / z + cy;

    const float4 q4 = ((const float4*)rots_raw)[i];
    float qw = q4.x, qx = q4.y, qy = q4.z, qz = q4.w;
    const float qn = sqrtf(qw * qw + qx * qx + qy * qy + qz * qz);
    qw /= qn; qx /= qn; qy /= qn; qz /= qn;
    float Rr[3][3];
    Rr[0][0] = 1.f - 2.f * (qy * qy + qz * qz);
    Rr[0][1] = 2.f * (qx * qy - qw * qz);
    Rr[0][2] = 2.f * (qx * qz + qw * qy);
    Rr[1][0] = 2.f * (qx * qy + qw * qz);
    Rr[1][1] = 1.f - 2.f * (qx * qx + qz * qz);
    Rr[1][2] = 2.f * (qy * qz - qw * qx);
    Rr[2][0] = 2.f * (qx * qz - qw * qy);
    Rr[2][1] = 2.f * (qy * qz + qw * qx);
    Rr[2][2] = 1.f - 2.f * (qx * qx + qy * qy);

    const float s0 = expf(scales_raw[i * 3 + 0]);
    const float s1 = expf(scales_raw[i * 3 + 1]);
    const float s2 = expf(scales_raw[i * 3 + 2]);
    const float sc[3] = { s0, s1, s2 };

    float M[3][3];
    for (int r = 0; r < 3; ++r)
        for (int c = 0; c < 3; ++c) M[r][c] = Rr[r][c] * sc[c];

    float cov[3][3];
    for (int r = 0; r < 3; ++r)
        for (int c = 0; c < 3; ++c)
            cov[r][c] = M[r][0] * M[c][0] + M[r][1] * M[c][1] + M[r][2] * M[c][2];

    const float limx = 1.3f * 0.5f * (float)IMG_W / fx;
    const float limy = 1.3f * 0.5f * (float)IMG_H / fy;
    const float xz_ = pcx / z, yz_ = pcy / z;
    const float tx = fminf(fmaxf(xz_, -limx), limx) * z;
    const float ty = fminf(fmaxf(yz_, -limy), limy) * z;
    const float J00 = fx / z, J02 = -fx * tx / (z * z);
    const float J11 = fy / z, J12 = -fy * ty / (z * z);
    const float T00 = J00 * R00 + J02 * R20;
    const float T01 = J00 * R01 + J02 * R21;
    const float T02 = J00 * R02 + J02 * R22;
    const float T10 = J11 * R10 + J12 * R20;
    const float T11 = J11 * R11 + J12 * R21;
    const float T12 = J11 * R12 + J12 * R22;

    float tmp0[3], tmp1[3];
    for (int k = 0; k < 3; ++k) {
        tmp0[k] = T00 * cov[0][k] + T01 * cov[1][k] + T02 * cov[2][k];
        tmp1[k] = T10 * cov[0][k] + T11 * cov[1][k] + T12 * cov[2][k];
    }
    const float a = tmp0[0] * T00 + tmp0[1] * T01 + tmp0[2] * T02 + 0.3f;
    const float b = tmp0[0] * T10 + tmp0[1] * T11 + tmp0[2] * T12;
    const float c = tmp1[0] * T10 + tmp1[1] * T11 + tmp1[2] * T12 + 0.3f;

    const float twx = -(R00 * t0 + R10 * t1 + R20 * t2);
    const float twy = -(R01 * t0 + R11 * t1 + R21 * t2);
    const float twz = -(R02 * t0 + R12 * t1 + R22 * t2);
    const float ddx = pwx - twx, ddy = pwy - twy, ddz = pwz - twz;
    const float dn = sqrtf(ddx * ddx + ddy * ddy + ddz * ddz);
    const float dirx = ddx / dn, diry = ddy / dn, dirz = ddz / dn;

    const float xx = dirx * dirx, yy = diry * diry, zz = dirz * dirz;
    const float xy = dirx * diry, yz = diry * dirz, xz = dirx * dirz;
    float bf[16];
    bf[0]  = 0.28209479177387814f;
    bf[1]  = -0.4886025119029199f * diry;
    bf[2]  = 0.4886025119029199f * dirz;
    bf[3]  = -0.4886025119029199f * dirx;
    bf[4]  = 1.0925484305920792f * xy;
    bf[5]  = -1.0925484305920792f * yz;
    bf[6]  = 0.31539156525252005f * (2.f * zz - xx - yy);
    bf[7]  = -1.0925484305920792f * xz;
    bf[8]  = 0.5462742152960396f * (xx - yy);
    bf[9]  = -0.5900435899266435f * diry * (3.f * xx - yy);
    bf[10] = 2.890611442640554f * xy * dirz;
    bf[11] = -0.4570457994644658f * diry * (4.f * zz - xx - yy);
    bf[12] = 0.3731763325901154f * dirz * (2.f * zz - 3.f * xx - 3.f * yy);
    bf[13] = -0.4570457994644658f * dirx * (4.f * zz - xx - yy);
    bf[14] = 1.445305721320277f * dirz * (xx - yy);
    bf[15] = -0.5900435899266435f * dirx * (xx - 3.f * yy);

    // vectorized SH load: 48 contiguous floats = 12 float4
    float sh[48];
    const float4* sh4 = (const float4*)(shs + i * 48);
    #pragma unroll
    for (int k = 0; k < 12; ++k) ((float4*)sh)[k] = sh4[k];

    float col[3];
    for (int ch = 0; ch < 3; ++ch) {
        float acc = 0.f;
        #pragma unroll
        for (int k = 0; k < 16; ++k) acc += bf[k] * sh[k * 3 + ch];
        col[ch] = fmaxf(acc + 0.5f, 0.f);
    }

    const float det = a * c - b * b;
    valid = valid && (det > 0.f);
    const float det_s = valid ? det : 1.0f;
    const float ci0 = c / det_s, ci1 = -b / det_s, ci2 = a / det_s;

    const float mid  = 0.5f * (a + c);
    const float disc = sqrtf(fmaxf(mid * mid - det, 0.1f));
    const float lam0 = fmaxf(mid + disc, 0.f);       // lambda_max of cov2d
    const float a0 = 3.f * sqrtf(lam0);
    const float a1 = 3.f * sqrtf(fmaxf(mid - disc, 0.f));
    areas[i * 2 + 0] = valid ? a0 : 0.f;
    areas[i * 2 + 1] = valid ? a1 : 0.f;

    const float alpha = 1.f / (1.f + expf(-alphas_raw[i]));

    // conservative influence radius: g >= 1/255 needs 0.5*d^2/lam <= ln(255*al)
    // <= ln(255) = 5.541 -> d <= 3.329*sqrt(lam). Use 3.34 + 1.0 px margin
    // (covers pixel-center offset + half-precision rounding of rad).
    const bool vis = valid && (alpha >= (1.f / 255.f));
    const float rad = vis ? (3.34f * sqrtf(lam0) + 1.0f) : 0.f;

    depths[i] = depth;

    f2h2 pc; pc.h = __floats2half2_rn(col[0], col[1]);
    f2h2 cr; cr.h = __floats2half2_rn(col[2], rad);
    float* pk = packed + i * 8;
    pk[0] = ux;  pk[1] = uy;
    pk[2] = -0.5f * ci0; pk[3] = -ci1; pk[4] = -0.5f * ci2;
    pk[5] = vis ? alpha : 0.f;
    pk[6] = pc.f;
    pk[7] = cr.f;
}

// ---------------------------------------------------------------------------
// Kernel 2: rank sort, wave-per-splat. 256 blocks x 512 threads.
// Stable, matches jnp.argsort ascending exactly.
// ---------------------------------------------------------------------------
__global__ __launch_bounds__(512) void rank_scatter_k(
    const float* __restrict__ depths, const float4* __restrict__ packed,
    float4* __restrict__ sorted)
{
    __shared__ float sd[N_G];
    const int tid = threadIdx.x;
    ((float4*)sd)[tid] = ((const float4*)depths)[tid];   // 512 x float4 = 2048
    __syncthreads();

    const int w = tid >> 6, lane = tid & 63;
    const int i = blockIdx.x * 8 + w;
    const float d = sd[i];

    int r = 0;
    #pragma unroll 8
    for (int k = 0; k < 32; ++k) {
        const int j = k * 64 + lane;
        const float dj = sd[j];
        const bool c = (dj < d) || (dj == d && j < i);
        r += (int)__popcll(__ballot(c));
    }

    if (lane < 2)
        sorted[r * 2 + lane] = packed[i * 2 + lane];
}

// ---------------------------------------------------------------------------
// Kernel 3: rasterize with per-strip culling. 256 blocks x 1024 threads.
// Block = one 64-px strip (half row). Stage all 2048 sorted records (64 KB).
// Wave w owns ranks [w*128, (w+1)*128): for each 64-rank chunk, lanes test
// the strip bbox vs splat (center +- rad), ballot -> wave-uniform mask,
// then a scalar bit-loop composites only survivors (g==0 for the culled
// splats in the reference, so transmittance is unaffected).
// ---------------------------------------------------------------------------
__global__ __launch_bounds__(1024) void raster_k(
    const float4* __restrict__ sorted, float* __restrict__ image)
{
    __shared__ float4 sg[N_G * 2];               // 64 KB (reused for reduction)

    const int tid  = threadIdx.x;
    const int lane = tid & 63;
    const int w    = tid >> 6;

    #pragma unroll
    for (int k = 0; k < 4; ++k)
        sg[tid + k * 1024] = sorted[tid + k * 1024];
    __syncthreads();

    const int p = blockIdx.x * 64 + lane;
    const float px = (float)(p & (IMG_W - 1)) + 0.5f;
    const float py = (float)(p >> 7) + 0.5f;
    // strip bounds (same for all lanes of the block)
    const float x0f = (float)((blockIdx.x & 1) * 64) + 0.5f;   // first px center
    const float x1f = x0f + 63.0f;                              // last px center
    const float ycf = py;                                       // row center

    float T = 1.f, C0 = 0.f, C1 = 0.f, C2 = 0.f;

    #pragma unroll
    for (int cch = 0; cch < RSUB / 64; ++cch) {
        const int rbase = w * RSUB + cch * 64;
        // lane-parallel bbox test for 64 consecutive ranks
        const int rt = rbase + lane;
        const float tux = sg[rt * 2].x;
        const float tuy = sg[rt * 2].y;
        f2h2 tcr; tcr.f = sg[rt * 2 + 1].w;
        const float trad = __high2float(tcr.h);
        const bool hit = (fabsf(tuy - ycf) < trad) &&
                         (tux + trad > x0f) && (tux - trad < x1f);
        unsigned long long m = __ballot(hit);

        while (m) {
            const int b = (int)__builtin_ctzll(m);
            m &= (m - 1);
            const int rr = rbase + b;
            const float4 r0 = sg[rr * 2 + 0];
            const float4 r1 = sg[rr * 2 + 1];
            const float dx = px - r0.x, dy = py - r0.y;
            const float power = r0.z * (dx * dx) + r0.w * (dx * dy) + r1.x * (dy * dy);
            const float e = __expf(fminf(power, 0.f));
            float g = fminf(r1.y * e, 0.99f);
            const bool ok = (power <= 0.f) && (g >= (1.f / 255.f));
            g = ok ? g : 0.f;
            const float wgt = T * g;
            f2h2 cu; cu.f = r1.z;
            f2h2 cv; cv.f = r1.w;
            C0 += wgt * __low2float(cu.h);
            C1 += wgt * __high2float(cu.h);
            C2 += wgt * __low2float(cv.h);
            T *= (1.f - g);
        }
    }

    __syncthreads();                              // records no longer needed
    float4* red = sg;                             // [RWAVES][64] float4
    red[w * 64 + lane] = make_float4(C0, C1, C2, T);
    __syncthreads();

    if (w == 0) {
        float Tacc = 1.f, A0 = 0.f, A1 = 0.f, A2 = 0.f;
        #pragma unroll
        for (int s = 0; s < RWAVES; ++s) {
            const float4 v = red[s * 64 + lane];
            A0 += Tacc * v.x;
            A1 += Tacc * v.y;
            A2 += Tacc * v.z;
            Tacc *= v.w;
        }
        image[p]            = A0;
        image[NPIX + p]     = A1;
        image[2 * NPIX + p] = A2;
    }
}

// ---------------------------------------------------------------------------
extern "C" void kernel_launch(void* const* d_in, const int* in_sizes, int n_in,
                              void* d_out, int out_size, void* d_ws, size_t ws_size,
                              hipStream_t stream) {
    const float* pws        = (const float*)d_in[0];
    const float* shs        = (const float*)d_in[1];
    const float* alphas_raw = (const float*)d_in[2];
    const float* scales_raw = (const float*)d_in[3];
    const float* rots_raw   = (const float*)d_in[4];
    const float* Rcw        = (const float*)d_in[6];
    const float* tcw        = (const float*)d_in[7];
    const int*   fxp        = (const int*)d_in[8];
    const int*   fyp        = (const int*)d_in[9];
    const int*   cxp        = (const int*)d_in[10];
    const int*   cyp        = (const int*)d_in[11];

    float* out   = (float*)d_out;
    float* areas = out + 3 * NPIX;

    float* depths = (float*)d_ws;                  // 2048 f
    float* packed = depths + N_G;                  // 2048*8 f
    float* sorted = packed + N_G * 8;              // 2048*8 f

    preprocess_k<<<N_G / 64, 64, 0, stream>>>(
        pws, shs, alphas_raw, scales_raw, rots_raw, Rcw, tcw,
        fxp, fyp, cxp, cyp, areas, depths, packed);

    rank_scatter_k<<<N_G / 8, 512, 0, stream>>>(
        depths, (const float4*)packed, (float4*)sorted);

    raster_k<<<NPIX / 64, 1024, 0, stream>>>((const float4*)sorted, out);
}